// Round 1
// baseline (791.425 us; speedup 1.0000x reference)
//
#include <hip/hip_runtime.h>
#include <math.h>

#define Bsz 128
#define Ssz 2048
#define Esz 512
#define Hsz 512
#define C_CLIPF 10.0f
#define CHUNK 128   // rows of S per block in k_score -> grid = 128*16 = 2048 blocks

__device__ __forceinline__ float wave_reduce_sum(float p) {
    #pragma unroll
    for (int o = 32; o > 0; o >>= 1) p += __shfl_down(p, o);
    return p;
}

__device__ __forceinline__ float wave_reduce_max(float p) {
    #pragma unroll
    for (int o = 32; o > 0; o >>= 1) p = fmaxf(p, __shfl_down(p, o));
    return p;
}

// Kernel 1: per-b projections.
//   q[h] = bq[h] + <query[b,:], Wq[h,:]>      (held in LDS)
//   v[b,e] = sum_h q[h] * Wk[h,e]
//   c[b]  = <q, bk>
__global__ __launch_bounds__(512) void k_qv(
    const float* __restrict__ query, const float* __restrict__ Wq,
    const float* __restrict__ bq, const float* __restrict__ Wk,
    const float* __restrict__ bk, float* __restrict__ v, float* __restrict__ c)
{
    const int b = blockIdx.x;
    const int tid = threadIdx.x;
    const int wave = tid >> 6, lane = tid & 63;
    __shared__ float q[Hsz];
    __shared__ float cpart[8];

    // Each lane keeps its 8 query elements in registers (reused for all rows).
    const float4* qp = (const float4*)(query + (size_t)b * Esz);
    const float4 qy0 = qp[lane * 2], qy1 = qp[lane * 2 + 1];

    // Phase A: wave-per-row GEMV, coalesced float4 reads of Wq rows.
    for (int h = wave; h < Hsz; h += 8) {
        const float4* wr = (const float4*)(Wq + (size_t)h * Esz);
        const float4 a0 = wr[lane * 2], a1 = wr[lane * 2 + 1];
        float p = a0.x*qy0.x + a0.y*qy0.y + a0.z*qy0.z + a0.w*qy0.w
                + a1.x*qy1.x + a1.y*qy1.y + a1.z*qy1.z + a1.w*qy1.w;
        p = wave_reduce_sum(p);
        if (lane == 0) q[h] = p + bq[h];
    }
    __syncthreads();

    // c[b] = <q, bk>
    {
        float p = q[tid] * bk[tid];
        p = wave_reduce_sum(p);
        if (lane == 0) cpart[wave] = p;
    }
    __syncthreads();
    if (tid == 0) {
        float s = 0.f;
        #pragma unroll
        for (int w = 0; w < 8; ++w) s += cpart[w];
        c[b] = s;
    }

    // Phase B: v[e] = sum_h q[h] * Wk[h,e]; q[h] is an LDS broadcast (free),
    // Wk reads are row-major coalesced across the 512 threads.
    float acc = 0.f;
    #pragma unroll 4
    for (int h = 0; h < Hsz; ++h) acc += q[h] * Wk[(size_t)h * Esz + tid];
    v[(size_t)b * Esz + tid] = acc;
}

// Kernel 2: the streaming pass. score[b,s] = mask ? -inf : 10*tanh(<target[b,s,:], v[b,:]> + c[b])
// One wave per row; 2 KiB contiguous per row (2x float4 per lane). Writes into d_out.
__global__ __launch_bounds__(256) void k_score(
    const float* __restrict__ target, const int* __restrict__ mask,
    const float* __restrict__ v, const float* __restrict__ c,
    float* __restrict__ scores)
{
    const int nchunk = Ssz / CHUNK;
    const int b = blockIdx.x / nchunk;
    const int s0 = (blockIdx.x % nchunk) * CHUNK;
    const int wave = threadIdx.x >> 6, lane = threadIdx.x & 63;

    const float4* vp = (const float4*)(v + (size_t)b * Esz);
    const float4 v0 = vp[lane * 2], v1 = vp[lane * 2 + 1];
    const float cb = c[b];

    for (int r = wave; r < CHUNK; r += 4) {
        const int s = s0 + r;
        const float4* tp = (const float4*)(target + ((size_t)b * Ssz + s) * Esz);
        const float4 t0 = tp[lane * 2], t1 = tp[lane * 2 + 1];
        float p = t0.x*v0.x + t0.y*v0.y + t0.z*v0.z + t0.w*v0.w
                + t1.x*v1.x + t1.y*v1.y + t1.z*v1.z + t1.w*v1.w;
        p = wave_reduce_sum(p);
        if (lane == 0) {
            float sc;
            if (mask[(size_t)b * Ssz + s] == 1) sc = -INFINITY;
            else sc = C_CLIPF * tanhf(p + cb);
            scores[(size_t)b * Ssz + s] = sc;
        }
    }
}

// Kernel 3: in-place row softmax over d_out. 2048 elems/row, 256 threads, 8/thread.
__global__ __launch_bounds__(256) void k_softmax(float* __restrict__ out)
{
    const int b = blockIdx.x;
    const int tid = threadIdx.x;
    const int wave = tid >> 6, lane = tid & 63;
    __shared__ float red[4];

    float4* op = (float4*)(out + (size_t)b * Ssz);
    const float4 a0 = op[tid * 2], a1 = op[tid * 2 + 1];

    float m = fmaxf(fmaxf(fmaxf(a0.x, a0.y), fmaxf(a0.z, a0.w)),
                    fmaxf(fmaxf(a1.x, a1.y), fmaxf(a1.z, a1.w)));
    m = wave_reduce_max(m);
    if (lane == 0) red[wave] = m;
    __syncthreads();
    const float M = fmaxf(fmaxf(red[0], red[1]), fmaxf(red[2], red[3]));
    __syncthreads();

    float e0 = expf(a0.x - M), e1 = expf(a0.y - M), e2 = expf(a0.z - M), e3 = expf(a0.w - M);
    float e4 = expf(a1.x - M), e5 = expf(a1.y - M), e6 = expf(a1.z - M), e7 = expf(a1.w - M);

    float s = ((e0 + e1) + (e2 + e3)) + ((e4 + e5) + (e6 + e7));
    s = wave_reduce_sum(s);
    if (lane == 0) red[wave] = s;
    __syncthreads();
    const float SUM = ((red[0] + red[1]) + (red[2] + red[3]));
    const float inv = 1.0f / SUM;

    op[tid * 2]     = make_float4(e0 * inv, e1 * inv, e2 * inv, e3 * inv);
    op[tid * 2 + 1] = make_float4(e4 * inv, e5 * inv, e6 * inv, e7 * inv);
}

extern "C" void kernel_launch(void* const* d_in, const int* in_sizes, int n_in,
                              void* d_out, int out_size, void* d_ws, size_t ws_size,
                              hipStream_t stream) {
    const float* query  = (const float*)d_in[0];
    const float* target = (const float*)d_in[1];
    const int*   mask   = (const int*)d_in[2];
    const float* Wq     = (const float*)d_in[3];
    const float* bq     = (const float*)d_in[4];
    const float* Wk     = (const float*)d_in[5];
    const float* bk     = (const float*)d_in[6];
    float* out = (float*)d_out;

    float* v = (float*)d_ws;            // [B, E] = 256 KiB
    float* c = v + (size_t)Bsz * Esz;   // [B]

    hipLaunchKernelGGL(k_qv, dim3(Bsz), dim3(512), 0, stream,
                       query, Wq, bq, Wk, bk, v, c);
    hipLaunchKernelGGL(k_score, dim3(Bsz * (Ssz / CHUNK)), dim3(256), 0, stream,
                       target, mask, v, c, out);
    hipLaunchKernelGGL(k_softmax, dim3(Bsz), dim3(256), 0, stream, out);
}

// Round 4
// 789.338 us; speedup vs baseline: 1.0026x; 1.0026x over previous
//
#include <hip/hip_runtime.h>
#include <math.h>

#define Bsz 128
#define Ssz 2048
#define Esz 512
#define Hsz 512
#define C_CLIPF 10.0f
#define CHUNK 256                      // rows of S per block in k_score
#define NCHUNK (Ssz / CHUNK)           // 8
#define NBLK (Bsz * NCHUNK)            // 1024 blocks

__device__ __forceinline__ float wave_reduce_sum(float p) {
    #pragma unroll
    for (int o = 32; o > 0; o >>= 1) p += __shfl_down(p, o);
    return p;
}

__device__ __forceinline__ float wave_reduce_max(float p) {
    #pragma unroll
    for (int o = 32; o > 0; o >>= 1) p = fmaxf(p, __shfl_down(p, o));
    return p;
}

// One step of the value-merging butterfly: lanes with (sel==0) keep `a` and
// receive the partner's `a`; lanes with (sel!=0) keep `b` and receive the
// partner's `b`. Halves the value count per step.
__device__ __forceinline__ float merge_step(float a, float b, int xmask, int sel) {
    float keep = sel ? b : a;
    float send = sel ? a : b;
    return keep + __shfl_xor(send, xmask);
}

// Kernel 1: per-b projections.
//   q[h] = bq[h] + <query[b,:], Wq[h,:]>   (LDS)
//   v[b,e] = sum_h q[h] * Wk[h,e]
//   c[b]  = <q, bk>
__global__ __launch_bounds__(512) void k_qv(
    const float* __restrict__ query, const float* __restrict__ Wq,
    const float* __restrict__ bq, const float* __restrict__ Wk,
    const float* __restrict__ bk, float* __restrict__ v, float* __restrict__ c)
{
    const int b = blockIdx.x;
    const int tid = threadIdx.x;
    const int wave = tid >> 6, lane = tid & 63;
    __shared__ float q[Hsz];
    __shared__ float cpart[8];

    const float4* qp = (const float4*)(query + (size_t)b * Esz);
    const float4 qy0 = qp[lane * 2], qy1 = qp[lane * 2 + 1];

    // Phase A: wave-per-row GEMV over Wq (coalesced 2 KiB row reads).
    for (int h = wave; h < Hsz; h += 8) {
        const float4* wr = (const float4*)(Wq + (size_t)h * Esz);
        const float4 a0 = wr[lane * 2], a1 = wr[lane * 2 + 1];
        float p = a0.x*qy0.x + a0.y*qy0.y + a0.z*qy0.z + a0.w*qy0.w
                + a1.x*qy1.x + a1.y*qy1.y + a1.z*qy1.z + a1.w*qy1.w;
        p = wave_reduce_sum(p);
        if (lane == 0) q[h] = p + bq[h];
    }
    __syncthreads();

    // c[b] = <q, bk>
    {
        float p = q[tid] * bk[tid];
        p = wave_reduce_sum(p);
        if (lane == 0) cpart[wave] = p;
    }
    __syncthreads();
    if (tid == 0) {
        float s = 0.f;
        #pragma unroll
        for (int w = 0; w < 8; ++w) s += cpart[w];
        c[b] = s;
    }

    // Phase B: v[e] = sum_h q[h] * Wk[h,e]; coalesced row reads, unroll 8 for MLP.
    float acc = 0.f;
    #pragma unroll 8
    for (int h = 0; h < Hsz; ++h) acc += q[h] * Wk[(size_t)h * Esz + tid];
    v[(size_t)b * Esz + tid] = acc;
}

// Kernel 2: pure streaming dot. scores[b,s] = <target[b,s,:], v[b,:]>
// 8 rows in flight per wave (16 KiB independent loads), value-merging
// butterfly reduce (10 shuffles / 8 rows), coalesced 32 B store by lanes 0-7.
__global__ __launch_bounds__(256) void k_score(
    const float* __restrict__ target,
    const float* __restrict__ v,
    float* __restrict__ scores)
{
    const int b = blockIdx.x / NCHUNK;
    const int s0 = (blockIdx.x % NCHUNK) * CHUNK;
    const int wave = threadIdx.x >> 6, lane = threadIdx.x & 63;

    const float4* vp = (const float4*)(v + (size_t)b * Esz);
    const float4 v0 = vp[lane * 2], v1 = vp[lane * 2 + 1];

    const int rbase = s0 + wave * 64;          // 64 rows per wave
    const float4* tp = (const float4*)(target + ((size_t)b * Ssz + rbase) * Esz);
    float* op = scores + (size_t)b * Ssz + rbase;

    for (int it = 0; it < 8; ++it) {           // 8 iterations x 8 rows
        const float4* tpi = tp + (size_t)it * 8 * 128;
        float4 ta[8], tb[8];
        #pragma unroll
        for (int i = 0; i < 8; ++i) {
            ta[i] = tpi[i * 128 + lane * 2];
            tb[i] = tpi[i * 128 + lane * 2 + 1];
        }
        float p[8];
        #pragma unroll
        for (int i = 0; i < 8; ++i) {
            p[i] = ta[i].x*v0.x + ta[i].y*v0.y + ta[i].z*v0.z + ta[i].w*v0.w
                 + tb[i].x*v1.x + tb[i].y*v1.y + tb[i].z*v1.z + tb[i].w*v1.w;
        }
        // merge 8 values -> 1 value/lane (row = lane&7), then full-group sum
        float q0 = merge_step(p[0], p[1], 1, lane & 1);
        float q1 = merge_step(p[2], p[3], 1, lane & 1);
        float q2 = merge_step(p[4], p[5], 1, lane & 1);
        float q3 = merge_step(p[6], p[7], 1, lane & 1);
        float r0 = merge_step(q0, q1, 2, lane & 2);
        float r1 = merge_step(q2, q3, 2, lane & 2);
        float s  = merge_step(r0, r1, 4, lane & 4);
        s += __shfl_xor(s, 8);
        s += __shfl_xor(s, 16);
        s += __shfl_xor(s, 32);
        if (lane < 8) op[it * 8 + lane] = s;   // rows rbase+it*8 .. +7
    }
}

// Kernel 3: fused bias + 10*tanh + mask + row softmax, in-place on d_out.
__global__ __launch_bounds__(256) void k_softmax(
    const int* __restrict__ mask, const float* __restrict__ c,
    float* __restrict__ out)
{
    const int b = blockIdx.x;
    const int tid = threadIdx.x;
    const int wave = tid >> 6, lane = tid & 63;
    __shared__ float red[4];

    const float cb = c[b];
    float4* op = (float4*)(out + (size_t)b * Ssz);
    const int4* mp = (const int4*)(mask + (size_t)b * Ssz);

    const float4 a0 = op[tid * 2], a1 = op[tid * 2 + 1];
    const int4  m0 = mp[tid * 2], m1 = mp[tid * 2 + 1];

    float x[8] = {a0.x, a0.y, a0.z, a0.w, a1.x, a1.y, a1.z, a1.w};
    const int mm[8] = {m0.x, m0.y, m0.z, m0.w, m1.x, m1.y, m1.z, m1.w};

    #pragma unroll
    for (int i = 0; i < 8; ++i) {
        const float y = x[i] + cb;
        // tanh(y) = 1 - 2/(exp2(y*2*log2(e)) + 1); saturates correctly at +-inf
        const float t = 1.0f - 2.0f / (exp2f(y * 2.88539008177793f) + 1.0f);
        x[i] = (mm[i] == 1) ? -INFINITY : C_CLIPF * t;
    }

    float m = x[0];
    #pragma unroll
    for (int i = 1; i < 8; ++i) m = fmaxf(m, x[i]);
    m = wave_reduce_max(m);
    if (lane == 0) red[wave] = m;
    __syncthreads();
    const float M = fmaxf(fmaxf(red[0], red[1]), fmaxf(red[2], red[3]));
    __syncthreads();

    float e[8];
    float s = 0.f;
    #pragma unroll
    for (int i = 0; i < 8; ++i) { e[i] = expf(x[i] - M); s += e[i]; }
    s = wave_reduce_sum(s);
    if (lane == 0) red[wave] = s;
    __syncthreads();
    const float inv = 1.0f / (((red[0] + red[1]) + (red[2] + red[3])));

    op[tid * 2]     = make_float4(e[0]*inv, e[1]*inv, e[2]*inv, e[3]*inv);
    op[tid * 2 + 1] = make_float4(e[4]*inv, e[5]*inv, e[6]*inv, e[7]*inv);
}

extern "C" void kernel_launch(void* const* d_in, const int* in_sizes, int n_in,
                              void* d_out, int out_size, void* d_ws, size_t ws_size,
                              hipStream_t stream) {
    const float* query  = (const float*)d_in[0];
    const float* target = (const float*)d_in[1];
    const int*   mask   = (const int*)d_in[2];
    const float* Wq     = (const float*)d_in[3];
    const float* bq     = (const float*)d_in[4];
    const float* Wk     = (const float*)d_in[5];
    const float* bk     = (const float*)d_in[6];
    float* out = (float*)d_out;

    float* v = (float*)d_ws;            // [B, E] = 256 KiB
    float* c = v + (size_t)Bsz * Esz;   // [B]

    hipLaunchKernelGGL(k_qv, dim3(Bsz), dim3(512), 0, stream,
                       query, Wq, bq, Wk, bk, v, c);
    hipLaunchKernelGGL(k_score, dim3(NBLK), dim3(256), 0, stream,
                       target, v, out);
    hipLaunchKernelGGL(k_softmax, dim3(Bsz), dim3(256), 0, stream,
                       mask, c, out);
}

// Round 11
// 742.043 us; speedup vs baseline: 1.0665x; 1.0637x over previous
//
#include <hip/hip_runtime.h>
#include <math.h>

#define Bsz 128
#define Ssz 2048
#define Esz 512
#define Hsz 512
#define C_CLIPF 10.0f
#define CHUNK 256                      // rows of S per block in k_score
#define NCHUNK (Ssz / CHUNK)           // 8
#define NBLK (Bsz * NCHUNK)            // 1024 blocks

typedef float f4 __attribute__((ext_vector_type(4)));   // native clang vector:
// __builtin_nontemporal_load requires scalar/pointer/native-vector element type;
// HIP_vector_type (float4) is a struct and is rejected.

__device__ __forceinline__ float wave_reduce_sum(float p) {
    #pragma unroll
    for (int o = 32; o > 0; o >>= 1) p += __shfl_down(p, o);
    return p;
}

__device__ __forceinline__ float wave_reduce_max(float p) {
    #pragma unroll
    for (int o = 32; o > 0; o >>= 1) p = fmaxf(p, __shfl_down(p, o));
    return p;
}

// One step of the value-merging butterfly: lanes with (sel==0) keep `a` and
// receive the partner's `a`; lanes with (sel!=0) keep `b` and receive the
// partner's `b`. Halves the value count per step.
__device__ __forceinline__ float merge_step(float a, float b, int xmask, int sel) {
    float keep = sel ? b : a;
    float send = sel ? a : b;
    return keep + __shfl_xor(send, xmask);
}

// Kernel 1: per-b projections.
//   q[h] = bq[h] + <query[b,:], Wq[h,:]>   (LDS)
//   v[b,e] = sum_h q[h] * Wk[h,e]
//   c[b]  = <q, bk>
__global__ __launch_bounds__(512) void k_qv(
    const float* __restrict__ query, const float* __restrict__ Wq,
    const float* __restrict__ bq, const float* __restrict__ Wk,
    const float* __restrict__ bk, float* __restrict__ v, float* __restrict__ c)
{
    const int b = blockIdx.x;
    const int tid = threadIdx.x;
    const int wave = tid >> 6, lane = tid & 63;
    __shared__ float q[Hsz];
    __shared__ float cpart[8];

    const float4* qp = (const float4*)(query + (size_t)b * Esz);
    const float4 qy0 = qp[lane], qy1 = qp[64 + lane];

    // Phase A: wave-per-row GEMV over Wq (dense 1 KiB per load instruction).
    for (int h = wave; h < Hsz; h += 8) {
        const float4* wr = (const float4*)(Wq + (size_t)h * Esz);
        const float4 a0 = wr[lane], a1 = wr[64 + lane];
        float p = a0.x*qy0.x + a0.y*qy0.y + a0.z*qy0.z + a0.w*qy0.w
                + a1.x*qy1.x + a1.y*qy1.y + a1.z*qy1.z + a1.w*qy1.w;
        p = wave_reduce_sum(p);
        if (lane == 0) q[h] = p + bq[h];
    }
    __syncthreads();

    // c[b] = <q, bk>
    {
        float p = q[tid] * bk[tid];
        p = wave_reduce_sum(p);
        if (lane == 0) cpart[wave] = p;
    }
    __syncthreads();
    if (tid == 0) {
        float s = 0.f;
        #pragma unroll
        for (int w = 0; w < 8; ++w) s += cpart[w];
        c[b] = s;
    }

    // Phase B: v[e] = sum_h q[h] * Wk[h,e]; coalesced row reads, unroll 8 for MLP.
    float acc = 0.f;
    #pragma unroll 8
    for (int h = 0; h < Hsz; ++h) acc += q[h] * Wk[(size_t)h * Esz + tid];
    v[(size_t)b * Esz + tid] = acc;
}

// Kernel 2: pure streaming dot. scores[b,s] = <target[b,s,:], v[b,:]>
// 8 rows in flight per wave; DENSE loads: each instruction reads a contiguous
// 1 KiB half-row (lane i -> elements e = i*4..i*4+3 resp. 256+i*4..).
// Nontemporal: target has zero reuse, skip L2/L3 pollution.
__global__ __launch_bounds__(256) void k_score(
    const float* __restrict__ target,
    const float* __restrict__ v,
    float* __restrict__ scores)
{
    const int b = blockIdx.x / NCHUNK;
    const int s0 = (blockIdx.x % NCHUNK) * CHUNK;
    const int wave = threadIdx.x >> 6, lane = threadIdx.x & 63;

    const f4* vp = (const f4*)(v + (size_t)b * Esz);
    const f4 v0 = vp[lane], v1 = vp[64 + lane];

    const int rbase = s0 + wave * 64;          // 64 rows per wave
    const f4* tp = (const f4*)(target + ((size_t)b * Ssz + rbase) * Esz);
    float* op = scores + (size_t)b * Ssz + rbase;

    for (int it = 0; it < 8; ++it) {           // 8 iterations x 8 rows
        const f4* tpi = tp + (size_t)it * 8 * 128;
        f4 ta[8], tb[8];
        #pragma unroll
        for (int i = 0; i < 8; ++i) {
            ta[i] = __builtin_nontemporal_load(&tpi[i * 128 + lane]);
            tb[i] = __builtin_nontemporal_load(&tpi[i * 128 + 64 + lane]);
        }
        float p[8];
        #pragma unroll
        for (int i = 0; i < 8; ++i) {
            f4 m = ta[i] * v0 + tb[i] * v1;
            p[i] = (m.x + m.y) + (m.z + m.w);
        }
        // merge 8 values -> 1 value/lane (row = lane&7), then full-group sum
        float q0 = merge_step(p[0], p[1], 1, lane & 1);
        float q1 = merge_step(p[2], p[3], 1, lane & 1);
        float q2 = merge_step(p[4], p[5], 1, lane & 1);
        float q3 = merge_step(p[6], p[7], 1, lane & 1);
        float r0 = merge_step(q0, q1, 2, lane & 2);
        float r1 = merge_step(q2, q3, 2, lane & 2);
        float s  = merge_step(r0, r1, 4, lane & 4);
        s += __shfl_xor(s, 8);
        s += __shfl_xor(s, 16);
        s += __shfl_xor(s, 32);
        if (lane < 8) op[it * 8 + lane] = s;   // rows rbase+it*8 .. +7
    }
}

// Kernel 3: fused bias + 10*tanh + mask + row softmax, in-place on d_out.
__global__ __launch_bounds__(256) void k_softmax(
    const int* __restrict__ mask, const float* __restrict__ c,
    float* __restrict__ out)
{
    const int b = blockIdx.x;
    const int tid = threadIdx.x;
    const int wave = tid >> 6, lane = tid & 63;
    __shared__ float red[4];

    const float cb = c[b];
    float4* op = (float4*)(out + (size_t)b * Ssz);
    const int4* mp = (const int4*)(mask + (size_t)b * Ssz);

    const float4 a0 = op[tid * 2], a1 = op[tid * 2 + 1];
    const int4  m0 = mp[tid * 2], m1 = mp[tid * 2 + 1];

    float x[8] = {a0.x, a0.y, a0.z, a0.w, a1.x, a1.y, a1.z, a1.w};
    const int mm[8] = {m0.x, m0.y, m0.z, m0.w, m1.x, m1.y, m1.z, m1.w};

    #pragma unroll
    for (int i = 0; i < 8; ++i) {
        const float y = x[i] + cb;
        // tanh(y) = 1 - 2/(exp2(y*2*log2(e)) + 1); saturates correctly at +-inf
        const float t = 1.0f - 2.0f / (exp2f(y * 2.88539008177793f) + 1.0f);
        x[i] = (mm[i] == 1) ? -INFINITY : C_CLIPF * t;
    }

    float m = x[0];
    #pragma unroll
    for (int i = 1; i < 8; ++i) m = fmaxf(m, x[i]);
    m = wave_reduce_max(m);
    if (lane == 0) red[wave] = m;
    __syncthreads();
    const float M = fmaxf(fmaxf(red[0], red[1]), fmaxf(red[2], red[3]));
    __syncthreads();

    float e[8];
    float s = 0.f;
    #pragma unroll
    for (int i = 0; i < 8; ++i) { e[i] = expf(x[i] - M); s += e[i]; }
    s = wave_reduce_sum(s);
    if (lane == 0) red[wave] = s;
    __syncthreads();
    const float inv = 1.0f / (((red[0] + red[1]) + (red[2] + red[3])));

    op[tid * 2]     = make_float4(e[0]*inv, e[1]*inv, e[2]*inv, e[3]*inv);
    op[tid * 2 + 1] = make_float4(e[4]*inv, e[5]*inv, e[6]*inv, e[7]*inv);
}

extern "C" void kernel_launch(void* const* d_in, const int* in_sizes, int n_in,
                              void* d_out, int out_size, void* d_ws, size_t ws_size,
                              hipStream_t stream) {
    const float* query  = (const float*)d_in[0];
    const float* target = (const float*)d_in[1];
    const int*   mask   = (const int*)d_in[2];
    const float* Wq     = (const float*)d_in[3];
    const float* bq     = (const float*)d_in[4];
    const float* Wk     = (const float*)d_in[5];
    const float* bk     = (const float*)d_in[6];
    float* out = (float*)d_out;

    float* v = (float*)d_ws;            // [B, E] = 256 KiB
    float* c = v + (size_t)Bsz * Esz;   // [B]

    hipLaunchKernelGGL(k_qv, dim3(Bsz), dim3(512), 0, stream,
                       query, Wq, bq, Wk, bk, v, c);
    hipLaunchKernelGGL(k_score, dim3(NBLK), dim3(256), 0, stream,
                       target, v, out);
    hipLaunchKernelGGL(k_softmax, dim3(Bsz), dim3(256), 0, stream,
                       mask, c, out);
}